// Round 2
// baseline (5890.220 us; speedup 1.0000x reference)
//
#include <hip/hip_runtime.h>
#include <hip/hip_cooperative_groups.h>

namespace cg = cooperative_groups;

typedef __attribute__((ext_vector_type(4))) float f32x4;
typedef __attribute__((ext_vector_type(8))) short bf16x8;

#define T_DIM 128
#define B_DIM 32
#define H_DIM 1024
#define V_DIM 32000
#define MROWS 4096  // T*B

__device__ __forceinline__ ushort f2bf(float f){
  union { float f; unsigned u; } x; x.f = f;
  unsigned u = x.u;
  unsigned r = (u + 0x7fffu + ((u >> 16) & 1u)) >> 16;
  return (ushort)r;
}
__device__ __forceinline__ float bf2f(ushort h){
  union { unsigned u; float f; } x; x.u = ((unsigned)h) << 16;
  return x.f;
}

__device__ __forceinline__ void async_copy16(void* lds, const void* g){
  __builtin_amdgcn_global_load_lds((const __attribute__((address_space(1))) void*)g,
                                   (__attribute__((address_space(3))) void*)lds, 16, 0, 0);
}

// ---------------- casts ----------------
__global__ void cast_bf16_kernel(const float* __restrict__ s, ushort* __restrict__ d, int n4){
  int stride = gridDim.x * blockDim.x;
  for (int i = blockIdx.x*blockDim.x + threadIdx.x; i < n4; i += stride){
    float4 v = ((const float4*)s)[i];
    ushort4 o = make_ushort4(f2bf(v.x), f2bf(v.y), f2bf(v.z), f2bf(v.w));
    ((ushort4*)d)[i] = o;
  }
}

// hi = bf16(v); lo = bf16(v - hi)
__global__ void cast_split_kernel(const float* __restrict__ s, ushort* __restrict__ dh,
                                  ushort* __restrict__ dl, int n4){
  int stride = gridDim.x * blockDim.x;
  for (int i = blockIdx.x*blockDim.x + threadIdx.x; i < n4; i += stride){
    float4 v = ((const float4*)s)[i];
    ushort4 h = make_ushort4(f2bf(v.x), f2bf(v.y), f2bf(v.z), f2bf(v.w));
    ushort4 l = make_ushort4(f2bf(v.x - bf2f(h.x)), f2bf(v.y - bf2f(h.y)),
                             f2bf(v.z - bf2f(h.z)), f2bf(v.w - bf2f(h.w)));
    ((ushort4*)dh)[i] = h;
    ((ushort4*)dl)[i] = l;
  }
}

// ---------------- m97-style bf16 GEMM: C[M][N] = A[M][K] * B[N][K]^T + bias ----------------
// order==1: tn-major with XCD chunking (needs gridDim % 8 == 0).
__global__ __launch_bounds__(256) void gemm_bt(
    const ushort* __restrict__ A, const ushort* __restrict__ B,
    float* __restrict__ C, const float* __restrict__ bias,
    int N, int K, int NTN, int order)
{
  __shared__ ushort lA[128*32];
  __shared__ ushort lB[128*32];
  int tid = threadIdx.x;
  int lane = tid & 63, wid = tid >> 6;
  int bid = blockIdx.x;
  int tm, tn;
  if (order){
    int cpx = gridDim.x >> 3;                 // ids per XCD
    int id = (bid & 7) * cpx + (bid >> 3);    // contiguous id range per XCD
    tn = id >> 5; tm = id & 31;               // tn-major: 32 consecutive ids share tn
  } else {
    tm = bid / NTN; tn = bid % NTN;
  }
  int row0 = tm << 7, col0 = tn << 7;

  f32x4 acc[4][4] = {};

  auto stage = [&](const ushort* __restrict__ g, ushort* l, int r0, int k0){
    int c = wid << 1;
    const ushort* s0 = g + (size_t)(r0 + (c<<4) + (lane>>2))*K + k0 + ((lane&3)<<3);
    async_copy16(l + (c<<9), s0);
    async_copy16(l + ((c+1)<<9), s0 + (size_t)16*K);
  };

  int nk = K >> 5;
  stage(A, lA, row0, 0);
  stage(B, lB, col0, 0);
  int wm = (wid >> 1) << 6, wn = (wid & 1) << 6;
  int kg = (lane >> 4) << 3;
  int ar = lane & 15;

  for (int kt = 0; kt < nk; ++kt){
    __syncthreads();
    bf16x8 af[4], bfr[4];
    #pragma unroll
    for (int mi = 0; mi < 4; ++mi) af[mi]  = *(const bf16x8*)&lA[(wm + mi*16 + ar)*32 + kg];
    #pragma unroll
    for (int ni = 0; ni < 4; ++ni) bfr[ni] = *(const bf16x8*)&lB[(wn + ni*16 + ar)*32 + kg];
    #pragma unroll
    for (int mi = 0; mi < 4; ++mi)
      #pragma unroll
      for (int ni = 0; ni < 4; ++ni)
        acc[mi][ni] = __builtin_amdgcn_mfma_f32_16x16x32_bf16(af[mi], bfr[ni], acc[mi][ni], 0, 0, 0);
    if (kt + 1 < nk){
      __syncthreads();
      stage(A, lA, row0, (kt+1) << 5);
      stage(B, lB, col0, (kt+1) << 5);
    }
  }

  int rr = (lane >> 4) << 2;
  #pragma unroll
  for (int mi = 0; mi < 4; ++mi){
    #pragma unroll
    for (int ni = 0; ni < 4; ++ni){
      int r  = row0 + wm + mi*16 + rr;
      int cc = col0 + wn + ni*16 + ar;
      float bb = bias ? bias[cc] : 0.f;
      #pragma unroll
      for (int q = 0; q < 4; ++q){
        size_t idx = (size_t)(r + q) * N + cc;
        C[idx] = acc[mi][ni][q] + bb;
      }
    }
  }
}

// ---------------- fused split-bf16 GEMM: C = Ah*Bh^T + Ah*Bl^T + Al*Bh^T ----------------
__global__ __launch_bounds__(256) void gemm_bt_split(
    const ushort* __restrict__ Ah, const ushort* __restrict__ Al,
    const ushort* __restrict__ Bh, const ushort* __restrict__ Bl,
    float* __restrict__ C, int N, int K, int NTN)
{
  __shared__ ushort lAh[128*32], lAl[128*32], lBh[128*32], lBl[128*32];
  int tid = threadIdx.x;
  int lane = tid & 63, wid = tid >> 6;
  int tm = blockIdx.x / NTN, tn = blockIdx.x % NTN;
  int row0 = tm << 7, col0 = tn << 7;

  f32x4 acc[4][4] = {};

  auto stage = [&](const ushort* __restrict__ g, ushort* l, int r0, int k0){
    int c = wid << 1;
    const ushort* s0 = g + (size_t)(r0 + (c<<4) + (lane>>2))*K + k0 + ((lane&3)<<3);
    async_copy16(l + (c<<9), s0);
    async_copy16(l + ((c+1)<<9), s0 + (size_t)16*K);
  };

  int nk = K >> 5;
  stage(Ah, lAh, row0, 0); stage(Al, lAl, row0, 0);
  stage(Bh, lBh, col0, 0); stage(Bl, lBl, col0, 0);
  int wm = (wid >> 1) << 6, wn = (wid & 1) << 6;
  int kg = (lane >> 4) << 3;
  int ar = lane & 15;

  for (int kt = 0; kt < nk; ++kt){
    __syncthreads();
    bf16x8 afh[4], afl[4], bfh[4], bfl[4];
    #pragma unroll
    for (int mi = 0; mi < 4; ++mi){
      afh[mi] = *(const bf16x8*)&lAh[(wm + mi*16 + ar)*32 + kg];
      afl[mi] = *(const bf16x8*)&lAl[(wm + mi*16 + ar)*32 + kg];
    }
    #pragma unroll
    for (int ni = 0; ni < 4; ++ni){
      bfh[ni] = *(const bf16x8*)&lBh[(wn + ni*16 + ar)*32 + kg];
      bfl[ni] = *(const bf16x8*)&lBl[(wn + ni*16 + ar)*32 + kg];
    }
    #pragma unroll
    for (int mi = 0; mi < 4; ++mi)
      #pragma unroll
      for (int ni = 0; ni < 4; ++ni){
        acc[mi][ni] = __builtin_amdgcn_mfma_f32_16x16x32_bf16(afh[mi], bfh[ni], acc[mi][ni], 0, 0, 0);
        acc[mi][ni] = __builtin_amdgcn_mfma_f32_16x16x32_bf16(afh[mi], bfl[ni], acc[mi][ni], 0, 0, 0);
        acc[mi][ni] = __builtin_amdgcn_mfma_f32_16x16x32_bf16(afl[mi], bfh[ni], acc[mi][ni], 0, 0, 0);
      }
    if (kt + 1 < nk){
      __syncthreads();
      stage(Ah, lAh, row0, (kt+1) << 5); stage(Al, lAl, row0, (kt+1) << 5);
      stage(Bh, lBh, col0, (kt+1) << 5); stage(Bl, lBl, col0, (kt+1) << 5);
    }
  }

  int rr = (lane >> 4) << 2;
  #pragma unroll
  for (int mi = 0; mi < 4; ++mi)
    #pragma unroll
    for (int ni = 0; ni < 4; ++ni){
      int r  = row0 + wm + mi*16 + rr;
      int cc = col0 + wn + ni*16 + ar;
      #pragma unroll
      for (int q = 0; q < 4; ++q)
        C[(size_t)(r + q) * N + cc] = acc[mi][ni][q];
    }
}

// ---------------- persistent recurrence: all 128 steps, grid.sync between ----------------
// 64 blocks x 512 threads. Block b: gate-cols [b*16, b*16+16) of BOTH gates.
// wave wid: kh = wid&1 (K half), mh = (wid>>1)&1 (batch half), gate = wid>>2.
__global__ __launch_bounds__(512, 1) void ran_all(
    const ushort* __restrict__ ch_init,
    ushort* __restrict__ cl0, ushort* __restrict__ cl1,
    float* __restrict__ cf0, float* __restrict__ cf1,
    const ushort* __restrict__ wh, const ushort* __restrict__ wl,
    const float* __restrict__ b_i, const float* __restrict__ b_f,
    const float* __restrict__ ixfx, const float* __restrict__ x_all,
    ushort* __restrict__ out_bf)
{
  cg::grid_group grid = cg::this_grid();
  __shared__ float part[8][64][4];   // per-wave partial acc (8 KB)
  __shared__ float gsm[2*32*16];     // sigmoid gates (4 KB)
  int tid = threadIdx.x, lane = tid & 63, wid = tid >> 6;
  int kh = wid & 1, mh = (wid >> 1) & 1, gate = wid >> 2;
  int nb = blockIdx.x << 4;
  int ar = lane & 15, kg = (lane >> 4) << 3;
  const ushort* brow_h = wh + (size_t)((gate<<10) + nb + ar) * H_DIM + (kh<<9);
  const ushort* brow_l = wl + (size_t)((gate<<10) + nb + ar) * H_DIM + (kh<<9);
  const float* bias = gate ? b_f : b_i;
  int um = tid >> 4, uk = tid & 15;           // update-phase element (512 = 32x16)

  for (int t = 0; t < T_DIM; ++t){
    const ushort* ah = t ? out_bf + (size_t)(t-1)*B_DIM*H_DIM : ch_init;
    const ushort* al = (t & 1) ? cl1 : cl0;
    const float*  ci = (t & 1) ? cf1 : cf0;
    float*  co = (t & 1) ? cf0 : cf1;
    ushort* lo = (t & 1) ? cl0 : cl1;
    const float* ixfx_t = ixfx + (size_t)t * B_DIM * 2048;
    const float* x_t    = x_all + (size_t)t * B_DIM * H_DIM;
    ushort* out_t = out_bf + (size_t)t * B_DIM * H_DIM;

    const ushort* arow_h = ah + (size_t)((mh<<4) + ar) * H_DIM + (kh<<9);
    const ushort* arow_l = al + (size_t)((mh<<4) + ar) * H_DIM + (kh<<9);
    // 3 independent accumulator streams -> dep-chain of 16, not 48
    f32x4 a0 = {}, a1 = {}, a2 = {};
    #pragma unroll 4
    for (int kk = 0; kk < 16; ++kk){
      int o = (kk<<5) + kg;
      bf16x8 vah = *(const bf16x8*)&arow_h[o];
      bf16x8 val = *(const bf16x8*)&arow_l[o];
      bf16x8 vbh = *(const bf16x8*)&brow_h[o];
      bf16x8 vbl = *(const bf16x8*)&brow_l[o];
      a0 = __builtin_amdgcn_mfma_f32_16x16x32_bf16(vah, vbh, a0, 0, 0, 0);
      a1 = __builtin_amdgcn_mfma_f32_16x16x32_bf16(vah, vbl, a1, 0, 0, 0);
      a2 = __builtin_amdgcn_mfma_f32_16x16x32_bf16(val, vbh, a2, 0, 0, 0);
    }
    f32x4 acc = a0 + a1 + a2;
    *(f32x4*)&part[wid][lane][0] = acc;
    __syncthreads();
    if (kh == 0){
      f32x4 sum = *(const f32x4*)&part[wid][lane][0] + *(const f32x4*)&part[wid+1][lane][0];
      int kgl = nb + ar;
      float bb = bias[kgl];
      #pragma unroll
      for (int q = 0; q < 4; ++q){
        int m = (mh<<4) + ((lane>>4)<<2) + q;
        float pre = sum[q] + bb + ixfx_t[m*2048 + (gate<<10) + kgl];
        gsm[((gate<<5) + m)*16 + ar] = 1.f / (1.f + expf(-pre));
      }
    }
    __syncthreads();
    {
      int col = nb + uk;
      float iv = gsm[(um<<4) + uk];
      float fv = gsm[((32 + um)<<4) + uk];
      float cv = ci[(um<<10) + col];
      float xv = x_t[(um<<10) + col];
      float cn = iv * xv + fv * cv;
      co[(um<<10) + col] = cn;
      ushort hi = f2bf(cn);
      out_t[(um<<10) + col] = hi;
      lo[(um<<10) + col] = f2bf(cn - bf2f(hi));
    }
    __threadfence();
    grid.sync();
  }
}

__global__ void init_c_kernel(const float* __restrict__ hidden, float* __restrict__ cf,
                              ushort* __restrict__ ch, ushort* __restrict__ cl){
  int i = blockIdx.x * blockDim.x + threadIdx.x;
  float v = hidden[i];
  cf[i] = v;
  ushort h = f2bf(v);
  ch[i] = h;
  cl[i] = f2bf(v - bf2f(h));
}

// ---------------- log_softmax: pass 1 computes lse[row] online, pass 2 subtracts ----------------
__global__ __launch_bounds__(256) void lse_kernel(const float* __restrict__ logits,
                                                  float* __restrict__ lse){
  __shared__ float sm[4], ss[4];
  size_t row = blockIdx.x;
  const float4* p4 = (const float4*)(logits + row * (size_t)V_DIM);
  int tid = threadIdx.x;
  float m = -1e30f, s = 0.f;
  for (int i = tid; i < V_DIM/4; i += 256){
    float4 v = p4[i];
    float vm = fmaxf(fmaxf(v.x, v.y), fmaxf(v.z, v.w));
    if (vm > m){ s *= expf(m - vm); m = vm; }
    s += expf(v.x - m) + expf(v.y - m) + expf(v.z - m) + expf(v.w - m);
  }
  #pragma unroll
  for (int o = 32; o; o >>= 1){
    float mo = __shfl_xor(m, o), so = __shfl_xor(s, o);
    float M = fmaxf(m, mo);
    s = s * expf(m - M) + so * expf(mo - M);
    m = M;
  }
  if ((tid & 63) == 0){ sm[tid >> 6] = m; ss[tid >> 6] = s; }
  __syncthreads();
  if (tid == 0){
    float M = fmaxf(fmaxf(sm[0], sm[1]), fmaxf(sm[2], sm[3]));
    float S = ss[0]*expf(sm[0]-M) + ss[1]*expf(sm[1]-M) + ss[2]*expf(sm[2]-M) + ss[3]*expf(sm[3]-M);
    lse[row] = M + logf(S);
  }
}

__global__ __launch_bounds__(256) void sub_kernel(float* __restrict__ logits,
                                                  const float* __restrict__ lse){
  size_t row = blockIdx.x;
  float l = lse[row];
  float4* p4 = (float4*)(logits + row * (size_t)V_DIM);
  for (int i = threadIdx.x; i < V_DIM/4; i += 256){
    float4 v = p4[i];
    v.x -= l; v.y -= l; v.z -= l; v.w -= l;
    p4[i] = v;
  }
}

__global__ void copy_f32_kernel(const float* __restrict__ s, float* __restrict__ d, int n){
  int i = blockIdx.x * blockDim.x + threadIdx.x;
  if (i < n) d[i] = s[i];
}

// ---------------- launch ----------------
extern "C" void kernel_launch(void* const* d_in, const int* in_sizes, int n_in,
                              void* d_out, int out_size, void* d_ws, size_t ws_size,
                              hipStream_t stream)
{
  const float* input  = (const float*)d_in[0];
  const float* hidden = (const float*)d_in[1];
  const float* w_ic   = (const float*)d_in[2];
  const float* w_ix   = (const float*)d_in[3];
  const float* w_fc   = (const float*)d_in[4];
  const float* w_fx   = (const float*)d_in[5];
  const float* b_i    = (const float*)d_in[6];
  const float* b_f    = (const float*)d_in[7];
  const float* W_out  = (const float*)d_in[8];
  const float* b_out  = (const float*)d_in[9];
  float* out = (float*)d_out;

  char* ws = (char*)d_ws;
  ushort* wout_bf = (ushort*)(ws + 0);          // 65,536,000 B
  ushort* in_hi   = (ushort*)(ws + 65536000);
  ushort* in_lo   = (ushort*)(ws + 73924608);
  ushort* wx_hi   = (ushort*)(ws + 82313216);   // [w_ix; w_fx]
  ushort* wx_lo   = (ushort*)(ws + 86507520);
  ushort* wc_hi   = (ushort*)(ws + 90701824);   // [w_ic; w_fc]
  ushort* wc_lo   = (ushort*)(ws + 94896128);
  ushort* out_bf  = (ushort*)(ws + 99090432);   // bf16(c_t) for all T
  float*  cf0     = (float*) (ws + 107479040);
  float*  cf1     = (float*) (ws + 107610112);
  ushort* ch_init = (ushort*)(ws + 107741184);  // 64 KB; reused as lse after recurrence
  ushort* cl0     = (ushort*)(ws + 107872256);
  ushort* cl1     = (ushort*)(ws + 107937792);
  float* ixfx = out;  // [4096][2048] scratch inside (later overwritten) logits region
  float* lse = (float*)ch_init;  // dead after ran_all's t=0

  cast_bf16_kernel <<<2048,256,0,stream>>>(W_out, wout_bf, V_DIM*H_DIM/4);
  cast_split_kernel<<<1024,256,0,stream>>>(input, in_hi, in_lo, MROWS*H_DIM/4);
  cast_split_kernel<<<256,256,0,stream>>>(w_ix, wx_hi,             wx_lo,             H_DIM*H_DIM/4);
  cast_split_kernel<<<256,256,0,stream>>>(w_fx, wx_hi+H_DIM*H_DIM, wx_lo+H_DIM*H_DIM, H_DIM*H_DIM/4);
  cast_split_kernel<<<256,256,0,stream>>>(w_ic, wc_hi,             wc_lo,             H_DIM*H_DIM/4);
  cast_split_kernel<<<256,256,0,stream>>>(w_fc, wc_hi+H_DIM*H_DIM, wc_lo+H_DIM*H_DIM, H_DIM*H_DIM/4);

  // ixfx = input @ [w_ix; w_fx]^T  (split-bf16, fused 3-product)
  gemm_bt_split<<<32*16,256,0,stream>>>(in_hi, in_lo, wx_hi, wx_lo, ixfx, 2048, H_DIM, 16);

  init_c_kernel<<<128,256,0,stream>>>(hidden, cf0, ch_init, cl0);

  {
    void* args[] = { (void*)&ch_init, (void*)&cl0, (void*)&cl1, (void*)&cf0, (void*)&cf1,
                     (void*)&wc_hi, (void*)&wc_lo, (void*)&b_i, (void*)&b_f,
                     (void*)&ixfx, (void*)&input, (void*)&out_bf };
    hipLaunchCooperativeKernel(reinterpret_cast<void*>(&ran_all),
                               dim3(64), dim3(512), args, 0, stream);
  }

  // logits = outputs @ W_out^T + b_out  (tn-major grid + XCD chunking)
  gemm_bt<<<32*250,256,0,stream>>>(out_bf, wout_bf, out, b_out, V_DIM, H_DIM, 250, 1);
  lse_kernel<<<4096,256,0,stream>>>(out, lse);
  sub_kernel<<<4096,256,0,stream>>>(out, lse);
  // t=127 (odd) wrote cf0
  copy_f32_kernel<<<128,256,0,stream>>>(cf0, out + (size_t)MROWS*V_DIM, B_DIM*H_DIM);
}

// Round 3
// 2361.641 us; speedup vs baseline: 2.4941x; 2.4941x over previous
//
#include <hip/hip_runtime.h>

typedef __attribute__((ext_vector_type(4))) float f32x4;
typedef __attribute__((ext_vector_type(8))) short bf16x8;

#define T_DIM 128
#define B_DIM 32
#define H_DIM 1024
#define V_DIM 32000
#define MROWS 4096  // T*B
#define NBLK 64     // persistent recurrence blocks

__device__ __forceinline__ ushort f2bf(float f){
  union { float f; unsigned u; } x; x.f = f;
  unsigned u = x.u;
  unsigned r = (u + 0x7fffu + ((u >> 16) & 1u)) >> 16;
  return (ushort)r;
}
__device__ __forceinline__ float bf2f(ushort h){
  union { unsigned u; float f; } x; x.u = ((unsigned)h) << 16;
  return x.f;
}

__device__ __forceinline__ void async_copy16(void* lds, const void* g){
  __builtin_amdgcn_global_load_lds((const __attribute__((address_space(1))) void*)g,
                                   (__attribute__((address_space(3))) void*)lds, 16, 0, 0);
}

// ---------------- casts ----------------
__global__ void cast_bf16_kernel(const float* __restrict__ s, ushort* __restrict__ d, int n4){
  int stride = gridDim.x * blockDim.x;
  for (int i = blockIdx.x*blockDim.x + threadIdx.x; i < n4; i += stride){
    float4 v = ((const float4*)s)[i];
    ushort4 o = make_ushort4(f2bf(v.x), f2bf(v.y), f2bf(v.z), f2bf(v.w));
    ((ushort4*)d)[i] = o;
  }
}

// hi = bf16(v); lo = bf16(v - hi)
__global__ void cast_split_kernel(const float* __restrict__ s, ushort* __restrict__ dh,
                                  ushort* __restrict__ dl, int n4){
  int stride = gridDim.x * blockDim.x;
  for (int i = blockIdx.x*blockDim.x + threadIdx.x; i < n4; i += stride){
    float4 v = ((const float4*)s)[i];
    ushort4 h = make_ushort4(f2bf(v.x), f2bf(v.y), f2bf(v.z), f2bf(v.w));
    ushort4 l = make_ushort4(f2bf(v.x - bf2f(h.x)), f2bf(v.y - bf2f(h.y)),
                             f2bf(v.z - bf2f(h.z)), f2bf(v.w - bf2f(h.w)));
    ((ushort4*)dh)[i] = h;
    ((ushort4*)dl)[i] = l;
  }
}

// ---------------- m97-style bf16 GEMM: C[M][N] = A[M][K] * B[N][K]^T + bias ----------------
// order==1: XCD x owns tm band {4x..4x+3}, tn-major sweep, tm-fast inner.
// Requires gridDim % 8 == 0 and M-tiles == 32.
__global__ __launch_bounds__(256) void gemm_bt(
    const ushort* __restrict__ A, const ushort* __restrict__ B,
    float* __restrict__ C, const float* __restrict__ bias,
    int N, int K, int NTN, int order)
{
  __shared__ ushort lA[128*32];
  __shared__ ushort lB[128*32];
  int tid = threadIdx.x;
  int lane = tid & 63, wid = tid >> 6;
  int bid = blockIdx.x;
  int tm, tn;
  if (order){
    int xcd = bid & 7, id = bid >> 3;
    tn = id >> 2;                 // B tile: fetched once per XCD, tm-fast reuse
    tm = (xcd << 2) | (id & 3);   // A band: 4 tm per XCD, L2-resident (1 MB)
  } else {
    tm = bid / NTN; tn = bid % NTN;
  }
  int row0 = tm << 7, col0 = tn << 7;

  f32x4 acc[4][4] = {};

  auto stage = [&](const ushort* __restrict__ g, ushort* l, int r0, int k0){
    int c = wid << 1;
    const ushort* s0 = g + (size_t)(r0 + (c<<4) + (lane>>2))*K + k0 + ((lane&3)<<3);
    async_copy16(l + (c<<9), s0);
    async_copy16(l + ((c+1)<<9), s0 + (size_t)16*K);
  };

  int nk = K >> 5;
  stage(A, lA, row0, 0);
  stage(B, lB, col0, 0);
  int wm = (wid >> 1) << 6, wn = (wid & 1) << 6;
  int kg = (lane >> 4) << 3;
  int ar = lane & 15;

  for (int kt = 0; kt < nk; ++kt){
    __syncthreads();
    bf16x8 af[4], bfr[4];
    #pragma unroll
    for (int mi = 0; mi < 4; ++mi) af[mi]  = *(const bf16x8*)&lA[(wm + mi*16 + ar)*32 + kg];
    #pragma unroll
    for (int ni = 0; ni < 4; ++ni) bfr[ni] = *(const bf16x8*)&lB[(wn + ni*16 + ar)*32 + kg];
    #pragma unroll
    for (int mi = 0; mi < 4; ++mi)
      #pragma unroll
      for (int ni = 0; ni < 4; ++ni)
        acc[mi][ni] = __builtin_amdgcn_mfma_f32_16x16x32_bf16(af[mi], bfr[ni], acc[mi][ni], 0, 0, 0);
    if (kt + 1 < nk){
      __syncthreads();
      stage(A, lA, row0, (kt+1) << 5);
      stage(B, lB, col0, (kt+1) << 5);
    }
  }

  int rr = (lane >> 4) << 2;
  #pragma unroll
  for (int mi = 0; mi < 4; ++mi){
    #pragma unroll
    for (int ni = 0; ni < 4; ++ni){
      int r  = row0 + wm + mi*16 + rr;
      int cc = col0 + wn + ni*16 + ar;
      float bb = bias ? bias[cc] : 0.f;
      #pragma unroll
      for (int q = 0; q < 4; ++q){
        size_t idx = (size_t)(r + q) * N + cc;
        C[idx] = acc[mi][ni][q] + bb;
      }
    }
  }
}

// ---------------- fused split-bf16 GEMM: C = Ah*Bh^T + Ah*Bl^T + Al*Bh^T ----------------
__global__ __launch_bounds__(256) void gemm_bt_split(
    const ushort* __restrict__ Ah, const ushort* __restrict__ Al,
    const ushort* __restrict__ Bh, const ushort* __restrict__ Bl,
    float* __restrict__ C, int N, int K, int NTN)
{
  __shared__ ushort lAh[128*32], lAl[128*32], lBh[128*32], lBl[128*32];
  int tid = threadIdx.x;
  int lane = tid & 63, wid = tid >> 6;
  int tm = blockIdx.x / NTN, tn = blockIdx.x % NTN;
  int row0 = tm << 7, col0 = tn << 7;

  f32x4 acc[4][4] = {};

  auto stage = [&](const ushort* __restrict__ g, ushort* l, int r0, int k0){
    int c = wid << 1;
    const ushort* s0 = g + (size_t)(r0 + (c<<4) + (lane>>2))*K + k0 + ((lane&3)<<3);
    async_copy16(l + (c<<9), s0);
    async_copy16(l + ((c+1)<<9), s0 + (size_t)16*K);
  };

  int nk = K >> 5;
  stage(Ah, lAh, row0, 0); stage(Al, lAl, row0, 0);
  stage(Bh, lBh, col0, 0); stage(Bl, lBl, col0, 0);
  int wm = (wid >> 1) << 6, wn = (wid & 1) << 6;
  int kg = (lane >> 4) << 3;
  int ar = lane & 15;

  for (int kt = 0; kt < nk; ++kt){
    __syncthreads();
    bf16x8 afh[4], afl[4], bfh[4], bfl[4];
    #pragma unroll
    for (int mi = 0; mi < 4; ++mi){
      afh[mi] = *(const bf16x8*)&lAh[(wm + mi*16 + ar)*32 + kg];
      afl[mi] = *(const bf16x8*)&lAl[(wm + mi*16 + ar)*32 + kg];
    }
    #pragma unroll
    for (int ni = 0; ni < 4; ++ni){
      bfh[ni] = *(const bf16x8*)&lBh[(wn + ni*16 + ar)*32 + kg];
      bfl[ni] = *(const bf16x8*)&lBl[(wn + ni*16 + ar)*32 + kg];
    }
    #pragma unroll
    for (int mi = 0; mi < 4; ++mi)
      #pragma unroll
      for (int ni = 0; ni < 4; ++ni){
        acc[mi][ni] = __builtin_amdgcn_mfma_f32_16x16x32_bf16(afh[mi], bfh[ni], acc[mi][ni], 0, 0, 0);
        acc[mi][ni] = __builtin_amdgcn_mfma_f32_16x16x32_bf16(afh[mi], bfl[ni], acc[mi][ni], 0, 0, 0);
        acc[mi][ni] = __builtin_amdgcn_mfma_f32_16x16x32_bf16(afl[mi], bfh[ni], acc[mi][ni], 0, 0, 0);
      }
    if (kt + 1 < nk){
      __syncthreads();
      stage(Ah, lAh, row0, (kt+1) << 5); stage(Al, lAl, row0, (kt+1) << 5);
      stage(Bh, lBh, col0, (kt+1) << 5); stage(Bl, lBl, col0, (kt+1) << 5);
    }
  }

  int rr = (lane >> 4) << 2;
  #pragma unroll
  for (int mi = 0; mi < 4; ++mi)
    #pragma unroll
    for (int ni = 0; ni < 4; ++ni){
      int r  = row0 + wm + mi*16 + rr;
      int cc = col0 + wn + ni*16 + ar;
      #pragma unroll
      for (int q = 0; q < 4; ++q)
        C[(size_t)(r + q) * N + cc] = acc[mi][ni][q];
    }
}

// ---------------- persistent recurrence v2 ----------------
// 64 blocks x 512 threads. Block b owns gate-cols [16b,16b+16) of BOTH gates.
// W slice (hi+lo) lives in LDS (padded rows). f32 c-state slice lives in LDS.
// Custom monotonic barrier: 1 atomicAdd(release) + acquire-spin per block per step.
__global__ __launch_bounds__(512) void ran_all(
    const ushort* __restrict__ ch_init,
    ushort* __restrict__ cl0, ushort* __restrict__ cl1,
    const float* __restrict__ hidden,
    const ushort* __restrict__ wh, const ushort* __restrict__ wl,
    const float* __restrict__ b_i, const float* __restrict__ b_f,
    const float* __restrict__ ixfx, const float* __restrict__ x_all,
    ushort* __restrict__ out_bf, float* __restrict__ hid_final,
    unsigned* __restrict__ bar)
{
  __shared__ ushort lWh[32*1032];     // 32 rows x (1024+8) pad -> 4-bank row stagger
  __shared__ ushort lWl[32*1032];
  __shared__ float part[8][64][4];
  __shared__ float gsm[2*32*16];
  __shared__ float cfl[32][16];

  int tid = threadIdx.x, lane = tid & 63, wid = tid >> 6;
  int kh = wid & 1, mh = (wid >> 1) & 1, gate = wid >> 2;
  int nb = blockIdx.x << 4;
  int ar = lane & 15, kg = (lane >> 4) << 3;
  int um = tid >> 4, uk = tid & 15;

  // one-time: W slice -> LDS (coalesced 16B units), c-state slice -> LDS
  #pragma unroll
  for (int u = 0; u < 8; ++u){
    int unit = u*512 + tid;              // 32 rows x 128 units
    int r = unit >> 7, off = (unit & 127) << 3;
    int g = r >> 4, c = r & 15;
    size_t gsrc = (size_t)((g<<10) + nb + c) * H_DIM + off;
    *(bf16x8*)&lWh[r*1032 + off] = *(const bf16x8*)&wh[gsrc];
    *(bf16x8*)&lWl[r*1032 + off] = *(const bf16x8*)&wl[gsrc];
  }
  cfl[um][uk] = hidden[(um<<10) + nb + uk];
  float bb = (gate ? b_f : b_i)[nb + ar];
  const ushort* bbase_h = &lWh[((gate<<4) + ar)*1032 + (kh<<9)];
  const ushort* bbase_l = &lWl[((gate<<4) + ar)*1032 + (kh<<9)];
  __syncthreads();

  for (int t = 0; t < T_DIM; ++t){
    const ushort* ah = t ? out_bf + (size_t)(t-1)*B_DIM*H_DIM : ch_init;
    const ushort* al = (t & 1) ? cl1 : cl0;
    ushort* lo = (t & 1) ? cl0 : cl1;
    const float* ixfx_t = ixfx + (size_t)t * (B_DIM*2048);
    const float* x_t    = x_all + (size_t)t * (B_DIM*H_DIM);
    ushort* out_t = out_bf + (size_t)t * (B_DIM*H_DIM);

    // prefetch read-only per-step data (hides L3 latency under MFMA chain)
    float xv = x_t[(um<<10) + nb + uk];
    float pix[4];
    if (kh == 0){
      #pragma unroll
      for (int q = 0; q < 4; ++q){
        int m = (mh<<4) + ((lane>>4)<<2) + q;
        pix[q] = ixfx_t[m*2048 + (gate<<10) + nb + ar];
      }
    }

    const ushort* arow_h = ah + (size_t)((mh<<4) + ar) * H_DIM + (kh<<9);
    const ushort* arow_l = al + (size_t)((mh<<4) + ar) * H_DIM + (kh<<9);
    f32x4 a0 = {}, a1 = {}, a2 = {};   // 3 streams -> dep chain 16
    #pragma unroll 4
    for (int kk = 0; kk < 16; ++kk){
      int o = (kk<<5) + kg;
      bf16x8 vah = *(const bf16x8*)&arow_h[o];
      bf16x8 val = *(const bf16x8*)&arow_l[o];
      bf16x8 vbh = *(const bf16x8*)&bbase_h[o];
      bf16x8 vbl = *(const bf16x8*)&bbase_l[o];
      a0 = __builtin_amdgcn_mfma_f32_16x16x32_bf16(vah, vbh, a0, 0, 0, 0);
      a1 = __builtin_amdgcn_mfma_f32_16x16x32_bf16(vah, vbl, a1, 0, 0, 0);
      a2 = __builtin_amdgcn_mfma_f32_16x16x32_bf16(val, vbh, a2, 0, 0, 0);
    }
    f32x4 acc = a0 + a1 + a2;
    *(f32x4*)&part[wid][lane][0] = acc;
    __syncthreads();
    if (kh == 0){
      f32x4 sum = *(const f32x4*)&part[wid][lane][0] + *(const f32x4*)&part[wid+1][lane][0];
      #pragma unroll
      for (int q = 0; q < 4; ++q){
        int m = (mh<<4) + ((lane>>4)<<2) + q;
        float pre = sum[q] + bb + pix[q];
        gsm[((gate<<5) + m)*16 + ar] = 1.f / (1.f + expf(-pre));
      }
    }
    __syncthreads();
    {
      int col = nb + uk;
      float iv = gsm[(um<<4) + uk];
      float fv = gsm[((32 + um)<<4) + uk];
      float cv = cfl[um][uk];
      float cn = iv * xv + fv * cv;
      cfl[um][uk] = cn;
      ushort hi = f2bf(cn);
      out_t[(um<<10) + col] = hi;
      lo[(um<<10) + col] = f2bf(cn - bf2f(hi));
      if (t == T_DIM-1) hid_final[(um<<10) + col] = cn;
    }
    __syncthreads();   // all waves' stores drained (vmcnt) before release
    if (tid == 0){
      __hip_atomic_fetch_add(bar, 1u, __ATOMIC_RELEASE, __HIP_MEMORY_SCOPE_AGENT);
      unsigned target = (unsigned)NBLK * (unsigned)(t + 1);
      while (__hip_atomic_load(bar, __ATOMIC_ACQUIRE, __HIP_MEMORY_SCOPE_AGENT) < target)
        __builtin_amdgcn_s_sleep(1);
    }
    __syncthreads();
  }
}

__global__ void init_c_kernel(const float* __restrict__ hidden,
                              ushort* __restrict__ ch, ushort* __restrict__ cl,
                              unsigned* __restrict__ bar){
  int i = blockIdx.x * blockDim.x + threadIdx.x;
  if (i == 0) *bar = 0;
  float v = hidden[i];
  ushort h = f2bf(v);
  ch[i] = h;
  cl[i] = f2bf(v - bf2f(h));
}

// ---------------- log_softmax: lse pass + subtract pass ----------------
__global__ __launch_bounds__(256) void lse_kernel(const float* __restrict__ logits,
                                                  float* __restrict__ lse){
  __shared__ float sm[4], ss[4];
  size_t row = blockIdx.x;
  const float4* p4 = (const float4*)(logits + row * (size_t)V_DIM);
  int tid = threadIdx.x;
  float m = -1e30f, s = 0.f;
  for (int i = tid; i < V_DIM/4; i += 256){
    float4 v = p4[i];
    float vm = fmaxf(fmaxf(v.x, v.y), fmaxf(v.z, v.w));
    if (vm > m){ s *= expf(m - vm); m = vm; }
    s += expf(v.x - m) + expf(v.y - m) + expf(v.z - m) + expf(v.w - m);
  }
  #pragma unroll
  for (int o = 32; o; o >>= 1){
    float mo = __shfl_xor(m, o), so = __shfl_xor(s, o);
    float M = fmaxf(m, mo);
    s = s * expf(m - M) + so * expf(mo - M);
    m = M;
  }
  if ((tid & 63) == 0){ sm[tid >> 6] = m; ss[tid >> 6] = s; }
  __syncthreads();
  if (tid == 0){
    float M = fmaxf(fmaxf(sm[0], sm[1]), fmaxf(sm[2], sm[3]));
    float S = ss[0]*expf(sm[0]-M) + ss[1]*expf(sm[1]-M) + ss[2]*expf(sm[2]-M) + ss[3]*expf(sm[3]-M);
    lse[row] = M + logf(S);
  }
}

__global__ __launch_bounds__(256) void sub_kernel(float* __restrict__ logits,
                                                  const float* __restrict__ lse){
  size_t row = blockIdx.x;
  float l = lse[row];
  float4* p4 = (float4*)(logits + row * (size_t)V_DIM);
  for (int i = threadIdx.x; i < V_DIM/4; i += 256){
    float4 v = p4[i];
    v.x -= l; v.y -= l; v.z -= l; v.w -= l;
    p4[i] = v;
  }
}

// ---------------- launch ----------------
extern "C" void kernel_launch(void* const* d_in, const int* in_sizes, int n_in,
                              void* d_out, int out_size, void* d_ws, size_t ws_size,
                              hipStream_t stream)
{
  const float* input  = (const float*)d_in[0];
  const float* hidden = (const float*)d_in[1];
  const float* w_ic   = (const float*)d_in[2];
  const float* w_ix   = (const float*)d_in[3];
  const float* w_fc   = (const float*)d_in[4];
  const float* w_fx   = (const float*)d_in[5];
  const float* b_i    = (const float*)d_in[6];
  const float* b_f    = (const float*)d_in[7];
  const float* W_out  = (const float*)d_in[8];
  const float* b_out  = (const float*)d_in[9];
  float* out = (float*)d_out;

  char* ws = (char*)d_ws;
  ushort* wout_bf = (ushort*)(ws + 0);          // 65,536,000 B
  ushort* in_hi   = (ushort*)(ws + 65536000);
  ushort* in_lo   = (ushort*)(ws + 73924608);
  ushort* wx_hi   = (ushort*)(ws + 82313216);   // [w_ix; w_fx]
  ushort* wx_lo   = (ushort*)(ws + 86507520);
  ushort* wc_hi   = (ushort*)(ws + 90701824);   // [w_ic; w_fc]
  ushort* wc_lo   = (ushort*)(ws + 94896128);
  ushort* out_bf  = (ushort*)(ws + 99090432);   // bf16(c_t) for all T
  unsigned* bar   = (unsigned*)(ws + 107479040);
  ushort* ch_init = (ushort*)(ws + 107741184);  // 64 KB; reused as lse after ran_all
  ushort* cl0     = (ushort*)(ws + 107872256);
  ushort* cl1     = (ushort*)(ws + 107937792);
  float* ixfx = out;  // [4096][2048] scratch inside (later overwritten) logits region
  float* lse = (float*)ch_init;  // dead after ran_all's t=0

  cast_bf16_kernel <<<2048,256,0,stream>>>(W_out, wout_bf, V_DIM*H_DIM/4);
  cast_split_kernel<<<1024,256,0,stream>>>(input, in_hi, in_lo, MROWS*H_DIM/4);
  cast_split_kernel<<<256,256,0,stream>>>(w_ix, wx_hi,             wx_lo,             H_DIM*H_DIM/4);
  cast_split_kernel<<<256,256,0,stream>>>(w_fx, wx_hi+H_DIM*H_DIM, wx_lo+H_DIM*H_DIM, H_DIM*H_DIM/4);
  cast_split_kernel<<<256,256,0,stream>>>(w_ic, wc_hi,             wc_lo,             H_DIM*H_DIM/4);
  cast_split_kernel<<<256,256,0,stream>>>(w_fc, wc_hi+H_DIM*H_DIM, wc_lo+H_DIM*H_DIM, H_DIM*H_DIM/4);

  // ixfx = input @ [w_ix; w_fx]^T  (split-bf16, fused 3-product)
  gemm_bt_split<<<32*16,256,0,stream>>>(in_hi, in_lo, wx_hi, wx_lo, ixfx, 2048, H_DIM, 16);

  init_c_kernel<<<128,256,0,stream>>>(hidden, ch_init, cl0, bar);

  ran_all<<<NBLK,512,0,stream>>>(ch_init, cl0, cl1, hidden, wc_hi, wc_lo, b_i, b_f,
                                 ixfx, input, out_bf, out + (size_t)MROWS*V_DIM, bar);

  // logits = outputs @ W_out^T + b_out  (XCD-banded grid)
  gemm_bt<<<32*250,256,0,stream>>>(out_bf, wout_bf, out, b_out, V_DIM, H_DIM, 250, 1);
  lse_kernel<<<4096,256,0,stream>>>(out, lse);
  sub_kernel<<<4096,256,0,stream>>>(out, lse);
}

// Round 4
// 2030.750 us; speedup vs baseline: 2.9005x; 1.1629x over previous
//
#include <hip/hip_runtime.h>

typedef __attribute__((ext_vector_type(4))) float f32x4;
typedef __attribute__((ext_vector_type(8))) short bf16x8;

#define T_DIM 128
#define B_DIM 32
#define H_DIM 1024
#define V_DIM 32000
#define MROWS 4096   // T*B
#define NBLK 64      // persistent recurrence blocks
#define CLSLOT (B_DIM*H_DIM)
#define WSTRIDE 1028 // LDS W row stride (ushorts): bank step 2 -> conflict-free

__device__ __forceinline__ ushort f2bf(float f){
  union { float f; unsigned u; } x; x.f = f;
  unsigned u = x.u;
  unsigned r = (u + 0x7fffu + ((u >> 16) & 1u)) >> 16;
  return (ushort)r;
}
__device__ __forceinline__ float bf2f(ushort h){
  union { unsigned u; float f; } x; x.u = ((unsigned)h) << 16;
  return x.f;
}

__device__ __forceinline__ void async_copy16(void* lds, const void* g){
  __builtin_amdgcn_global_load_lds((const __attribute__((address_space(1))) void*)g,
                                   (__attribute__((address_space(3))) void*)lds, 16, 0, 0);
}

// ---------------- casts ----------------
__global__ void cast_bf16_kernel(const float* __restrict__ s, ushort* __restrict__ d, int n4){
  int stride = gridDim.x * blockDim.x;
  for (int i = blockIdx.x*blockDim.x + threadIdx.x; i < n4; i += stride){
    float4 v = ((const float4*)s)[i];
    ushort4 o = make_ushort4(f2bf(v.x), f2bf(v.y), f2bf(v.z), f2bf(v.w));
    ((ushort4*)d)[i] = o;
  }
}

__global__ void cast_split_kernel(const float* __restrict__ s, ushort* __restrict__ dh,
                                  ushort* __restrict__ dl, int n4){
  int stride = gridDim.x * blockDim.x;
  for (int i = blockIdx.x*blockDim.x + threadIdx.x; i < n4; i += stride){
    float4 v = ((const float4*)s)[i];
    ushort4 h = make_ushort4(f2bf(v.x), f2bf(v.y), f2bf(v.z), f2bf(v.w));
    ushort4 l = make_ushort4(f2bf(v.x - bf2f(h.x)), f2bf(v.y - bf2f(h.y)),
                             f2bf(v.z - bf2f(h.z)), f2bf(v.w - bf2f(h.w)));
    ((ushort4*)dh)[i] = h;
    ((ushort4*)dl)[i] = l;
  }
}

// ---------------- m97-style bf16 GEMM + optional fused LSE partials ----------------
// C[M][N] = A[M][K]*B[N][K]^T + bias. order==1: XCD-banded mapping (gridDim%8==0, 32 M-tiles).
// If pmax!=nullptr: per (row, tn) write (max, sum(exp(v-max))) over this tile's 128 cols.
__global__ __launch_bounds__(256) void gemm_bt(
    const ushort* __restrict__ A, const ushort* __restrict__ B,
    float* __restrict__ C, const float* __restrict__ bias,
    int N, int K, int NTN, int order,
    float* __restrict__ pmax, float* __restrict__ psum)
{
  __shared__ ushort lA[128*32];
  __shared__ ushort lB[128*32];
  __shared__ float pmS[4][64], psS[4][64];
  int tid = threadIdx.x;
  int lane = tid & 63, wid = tid >> 6;
  int bid = blockIdx.x;
  int tm, tn;
  if (order){
    int xcd = bid & 7, id = bid >> 3;
    tn = id >> 2;                 // B tile fetched once per XCD
    tm = (xcd << 2) | (id & 3);   // 4-tm A band resident per XCD L2
  } else {
    tm = bid / NTN; tn = bid % NTN;
  }
  int row0 = tm << 7, col0 = tn << 7;

  f32x4 acc[4][4] = {};

  auto stage = [&](const ushort* __restrict__ g, ushort* l, int r0, int k0){
    int c = wid << 1;
    const ushort* s0 = g + (size_t)(r0 + (c<<4) + (lane>>2))*K + k0 + ((lane&3)<<3);
    async_copy16(l + (c<<9), s0);
    async_copy16(l + ((c+1)<<9), s0 + (size_t)16*K);
  };

  int nk = K >> 5;
  stage(A, lA, row0, 0);
  stage(B, lB, col0, 0);
  int wm = (wid >> 1) << 6, wn = (wid & 1) << 6;
  int kg = (lane >> 4) << 3;
  int ar = lane & 15;

  for (int kt = 0; kt < nk; ++kt){
    __syncthreads();
    bf16x8 af[4], bfr[4];
    #pragma unroll
    for (int mi = 0; mi < 4; ++mi) af[mi]  = *(const bf16x8*)&lA[(wm + mi*16 + ar)*32 + kg];
    #pragma unroll
    for (int ni = 0; ni < 4; ++ni) bfr[ni] = *(const bf16x8*)&lB[(wn + ni*16 + ar)*32 + kg];
    #pragma unroll
    for (int mi = 0; mi < 4; ++mi)
      #pragma unroll
      for (int ni = 0; ni < 4; ++ni)
        acc[mi][ni] = __builtin_amdgcn_mfma_f32_16x16x32_bf16(af[mi], bfr[ni], acc[mi][ni], 0, 0, 0);
    if (kt + 1 < nk){
      __syncthreads();
      stage(A, lA, row0, (kt+1) << 5);
      stage(B, lB, col0, (kt+1) << 5);
    }
  }

  int rr = (lane >> 4) << 2;
  float bb4[4];
  #pragma unroll
  for (int ni = 0; ni < 4; ++ni) bb4[ni] = bias ? bias[col0 + wn + ni*16 + ar] : 0.f;

  #pragma unroll
  for (int mi = 0; mi < 4; ++mi){
    #pragma unroll
    for (int q = 0; q < 4; ++q){
      int r = row0 + wm + mi*16 + rr + q;
      float vals[4];
      #pragma unroll
      for (int ni = 0; ni < 4; ++ni){
        vals[ni] = acc[mi][ni][q] + bb4[ni];
        C[(size_t)r * N + col0 + wn + ni*16 + ar] = vals[ni];
      }
      if (pmax){
        float m = fmaxf(fmaxf(vals[0], vals[1]), fmaxf(vals[2], vals[3]));
        #pragma unroll
        for (int o = 1; o < 16; o <<= 1) m = fmaxf(m, __shfl_xor(m, o));
        float s = expf(vals[0]-m) + expf(vals[1]-m) + expf(vals[2]-m) + expf(vals[3]-m);
        #pragma unroll
        for (int o = 1; o < 16; o <<= 1) s += __shfl_xor(s, o);
        if (ar == 0){ int rl = mi*16 + rr + q; pmS[wid][rl] = m; psS[wid][rl] = s; }
      }
    }
  }
  if (pmax){
    __syncthreads();
    if (tid < 128){
      int rl = tid & 63, half = tid >> 6;
      int w0 = half*2, w1 = w0 + 1;
      float m0 = pmS[w0][rl], m1 = pmS[w1][rl];
      float s0 = psS[w0][rl], s1 = psS[w1][rl];
      float M = fmaxf(m0, m1);
      float S = s0*expf(m0-M) + s1*expf(m1-M);
      int r = row0 + half*64 + rl;
      pmax[(size_t)r*NTN + tn] = M;
      psum[(size_t)r*NTN + tn] = S;
    }
  }
}

// ---------------- fused split-bf16 GEMM: C = Ah*Bh^T + Ah*Bl^T + Al*Bh^T ----------------
__global__ __launch_bounds__(256) void gemm_bt_split(
    const ushort* __restrict__ Ah, const ushort* __restrict__ Al,
    const ushort* __restrict__ Bh, const ushort* __restrict__ Bl,
    float* __restrict__ C, int N, int K, int NTN)
{
  __shared__ ushort lAh[128*32], lAl[128*32], lBh[128*32], lBl[128*32];
  int tid = threadIdx.x;
  int lane = tid & 63, wid = tid >> 6;
  int tm = blockIdx.x / NTN, tn = blockIdx.x % NTN;
  int row0 = tm << 7, col0 = tn << 7;

  f32x4 acc[4][4] = {};

  auto stage = [&](const ushort* __restrict__ g, ushort* l, int r0, int k0){
    int c = wid << 1;
    const ushort* s0 = g + (size_t)(r0 + (c<<4) + (lane>>2))*K + k0 + ((lane&3)<<3);
    async_copy16(l + (c<<9), s0);
    async_copy16(l + ((c+1)<<9), s0 + (size_t)16*K);
  };

  int nk = K >> 5;
  stage(Ah, lAh, row0, 0); stage(Al, lAl, row0, 0);
  stage(Bh, lBh, col0, 0); stage(Bl, lBl, col0, 0);
  int wm = (wid >> 1) << 6, wn = (wid & 1) << 6;
  int kg = (lane >> 4) << 3;
  int ar = lane & 15;

  for (int kt = 0; kt < nk; ++kt){
    __syncthreads();
    bf16x8 afh[4], afl[4], bfh[4], bfl[4];
    #pragma unroll
    for (int mi = 0; mi < 4; ++mi){
      afh[mi] = *(const bf16x8*)&lAh[(wm + mi*16 + ar)*32 + kg];
      afl[mi] = *(const bf16x8*)&lAl[(wm + mi*16 + ar)*32 + kg];
    }
    #pragma unroll
    for (int ni = 0; ni < 4; ++ni){
      bfh[ni] = *(const bf16x8*)&lBh[(wn + ni*16 + ar)*32 + kg];
      bfl[ni] = *(const bf16x8*)&lBl[(wn + ni*16 + ar)*32 + kg];
    }
    #pragma unroll
    for (int mi = 0; mi < 4; ++mi)
      #pragma unroll
      for (int ni = 0; ni < 4; ++ni){
        acc[mi][ni] = __builtin_amdgcn_mfma_f32_16x16x32_bf16(afh[mi], bfh[ni], acc[mi][ni], 0, 0, 0);
        acc[mi][ni] = __builtin_amdgcn_mfma_f32_16x16x32_bf16(afh[mi], bfl[ni], acc[mi][ni], 0, 0, 0);
        acc[mi][ni] = __builtin_amdgcn_mfma_f32_16x16x32_bf16(afl[mi], bfh[ni], acc[mi][ni], 0, 0, 0);
      }
    if (kt + 1 < nk){
      __syncthreads();
      stage(Ah, lAh, row0, (kt+1) << 5); stage(Al, lAl, row0, (kt+1) << 5);
      stage(Bh, lBh, col0, (kt+1) << 5); stage(Bl, lBl, col0, (kt+1) << 5);
    }
  }

  int rr = (lane >> 4) << 2;
  #pragma unroll
  for (int mi = 0; mi < 4; ++mi)
    #pragma unroll
    for (int ni = 0; ni < 4; ++ni){
      int r  = row0 + wm + mi*16 + rr;
      int cc = col0 + wn + ni*16 + ar;
      #pragma unroll
      for (int q = 0; q < 4; ++q)
        C[(size_t)(r + q) * N + cc] = acc[mi][ni][q];
    }
}

// ---------------- persistent recurrence v3: zero cache-maintenance steady state ----------------
// c published via write-through (sc1) relaxed-agent atomic stores; per-t cl slots so no reader
// address is ever stale-cacheable; relaxed arrival + relaxed polls (no wbl2/inv anywhere).
__global__ __launch_bounds__(512) void ran_all(
    const ushort* __restrict__ ch_init, const ushort* __restrict__ cl_init,
    ushort* __restrict__ cl_all, const float* __restrict__ hidden,
    const ushort* __restrict__ wh, const ushort* __restrict__ wl,
    const float* __restrict__ b_i, const float* __restrict__ b_f,
    const float* __restrict__ ixfx, const float* __restrict__ x_all,
    ushort* __restrict__ out_bf, float* __restrict__ hid_final,
    unsigned* __restrict__ bar)
{
  __shared__ ushort lWh[32*WSTRIDE];
  __shared__ ushort lWl[32*WSTRIDE];
  __shared__ float part[8][64][4];
  __shared__ float gsm[2*32*17];
  __shared__ float cfl[32][17];

  int tid = threadIdx.x, lane = tid & 63, wid = tid >> 6;
  int kh = wid & 1, mh = (wid >> 1) & 1, gate = wid >> 2;
  int nb = blockIdx.x << 4;
  int ar = lane & 15, kg = (lane >> 4) << 3;
  int um8 = tid >> 3, ukp = (tid & 7) << 1;   // update phase: 256 threads x 2 cols

  // one-time: W slice -> LDS, c-state f32 slice -> LDS
  #pragma unroll
  for (int u = 0; u < 8; ++u){
    int unit = u*512 + tid;
    int r = unit >> 7, off = (unit & 127) << 3;
    int g = r >> 4, c = r & 15;
    size_t gsrc = (size_t)((g<<10) + nb + c) * H_DIM + off;
    *(bf16x8*)&lWh[r*WSTRIDE + off] = *(const bf16x8*)&wh[gsrc];
    *(bf16x8*)&lWl[r*WSTRIDE + off] = *(const bf16x8*)&wl[gsrc];
  }
  if (tid < 256){
    cfl[um8][ukp]   = hidden[(um8<<10) + nb + ukp];
    cfl[um8][ukp+1] = hidden[(um8<<10) + nb + ukp + 1];
  }
  float bb = (gate ? b_f : b_i)[nb + ar];
  const ushort* bbase_h = &lWh[((gate<<4) + ar)*WSTRIDE + (kh<<9)];
  const ushort* bbase_l = &lWl[((gate<<4) + ar)*WSTRIDE + (kh<<9)];
  __syncthreads();

  for (int t = 0; t < T_DIM; ++t){
    const ushort* ah = t ? out_bf + (size_t)(t-1)*CLSLOT : ch_init;
    const ushort* al = t ? cl_all + (size_t)(t-1)*CLSLOT : cl_init;
    ushort* clw   = cl_all + (size_t)t*CLSLOT;
    ushort* out_t = out_bf + (size_t)t*CLSLOT;
    const float* ixfx_t = ixfx + (size_t)t * (B_DIM*2048);
    const float* x_t    = x_all + (size_t)t * (B_DIM*H_DIM);

    // prefetch read-only per-step data (overlaps the c loads + MFMA chain)
    float2 xv2;
    if (tid < 256) xv2 = *(const float2*)&x_t[(um8<<10) + nb + ukp];
    float pix[4];
    if (kh == 0){
      #pragma unroll
      for (int q = 0; q < 4; ++q){
        int m = (mh<<4) + ((lane>>4)<<2) + q;
        pix[q] = ixfx_t[m*2048 + (gate<<10) + nb + ar];
      }
    }

    const ushort* arow_h = ah + (size_t)((mh<<4) + ar) * H_DIM + (kh<<9);
    const ushort* arow_l = al + (size_t)((mh<<4) + ar) * H_DIM + (kh<<9);
    f32x4 a0 = {}, a1 = {}, a2 = {};   // 3 streams -> dep chain 16
    #pragma unroll 4
    for (int kk = 0; kk < 16; ++kk){
      int o = (kk<<5) + kg;
      bf16x8 vah = *(const bf16x8*)&arow_h[o];
      bf16x8 val = *(const bf16x8*)&arow_l[o];
      bf16x8 vbh = *(const bf16x8*)&bbase_h[o];
      bf16x8 vbl = *(const bf16x8*)&bbase_l[o];
      a0 = __builtin_amdgcn_mfma_f32_16x16x32_bf16(vah, vbh, a0, 0, 0, 0);
      a1 = __builtin_amdgcn_mfma_f32_16x16x32_bf16(vah, vbl, a1, 0, 0, 0);
      a2 = __builtin_amdgcn_mfma_f32_16x16x32_bf16(val, vbh, a2, 0, 0, 0);
    }
    f32x4 acc = a0 + a1 + a2;
    *(f32x4*)&part[wid][lane][0] = acc;
    __syncthreads();
    if (kh == 0){
      f32x4 sum = *(const f32x4*)&part[wid][lane][0] + *(const f32x4*)&part[wid+1][lane][0];
      #pragma unroll
      for (int q = 0; q < 4; ++q){
        int m = (mh<<4) + ((lane>>4)<<2) + q;
        float pre = sum[q] + bb + pix[q];
        gsm[((gate<<5) + m)*17 + ar] = 1.f / (1.f + expf(-pre));
      }
    }
    __syncthreads();
    if (tid < 256){
      int colb = (um8<<10) + nb + ukp;
      float iv0 = gsm[um8*17 + ukp],        iv1 = gsm[um8*17 + ukp + 1];
      float fv0 = gsm[(32+um8)*17 + ukp],   fv1 = gsm[(32+um8)*17 + ukp + 1];
      float c0 = cfl[um8][ukp], c1 = cfl[um8][ukp+1];
      float n0 = iv0*xv2.x + fv0*c0;
      float n1 = iv1*xv2.y + fv1*c1;
      cfl[um8][ukp] = n0; cfl[um8][ukp+1] = n1;
      ushort h0 = f2bf(n0), h1 = f2bf(n1);
      unsigned hp = (unsigned)h0 | ((unsigned)h1 << 16);
      unsigned lp = (unsigned)f2bf(n0 - bf2f(h0)) | ((unsigned)f2bf(n1 - bf2f(h1)) << 16);
      // write-through (sc1) so data reaches L3 before arrival; no wbl2 needed
      __hip_atomic_store((unsigned*)&out_t[colb], hp, __ATOMIC_RELAXED, __HIP_MEMORY_SCOPE_AGENT);
      __hip_atomic_store((unsigned*)&clw[colb],   lp, __ATOMIC_RELAXED, __HIP_MEMORY_SCOPE_AGENT);
      if (t == T_DIM-1){ hid_final[colb] = n0; hid_final[colb+1] = n1; }
    }
    if (t < T_DIM-1){
      __syncthreads();   // per-wave vmcnt(0) drain: all stores at coherence point
      if (tid == 0){
        __hip_atomic_fetch_add(bar, 1u, __ATOMIC_RELAXED, __HIP_MEMORY_SCOPE_AGENT);
        unsigned target = (unsigned)NBLK * (unsigned)(t + 1);
        while (__hip_atomic_load(bar, __ATOMIC_RELAXED, __HIP_MEMORY_SCOPE_AGENT) < target)
          __builtin_amdgcn_s_sleep(1);
      }
      __syncthreads();
    }
  }
}

__global__ void init_c_kernel(const float* __restrict__ hidden,
                              ushort* __restrict__ ch, ushort* __restrict__ cl,
                              unsigned* __restrict__ bar){
  int i = blockIdx.x * blockDim.x + threadIdx.x;
  if (i == 0) *bar = 0;
  float v = hidden[i];
  ushort h = f2bf(v);
  ch[i] = h;
  cl[i] = f2bf(v - bf2f(h));
}

// ---------------- lse reduce: 250 tile-partials -> lse[row] ----------------
__global__ __launch_bounds__(64) void lse_reduce(const float* __restrict__ pmax,
                                                 const float* __restrict__ psum,
                                                 float* __restrict__ lse, int ntn){
  int row = blockIdx.x, lane = threadIdx.x;
  float m = -1e30f, s = 0.f;
  for (int i = lane; i < ntn; i += 64){
    float mi = pmax[(size_t)row*ntn + i], si = psum[(size_t)row*ntn + i];
    float M = fmaxf(m, mi);
    s = s*expf(m - M) + si*expf(mi - M);
    m = M;
  }
  #pragma unroll
  for (int o = 32; o; o >>= 1){
    float m2 = __shfl_xor(m, o), s2 = __shfl_xor(s, o);
    float M = fmaxf(m, m2);
    s = s*expf(m - M) + s2*expf(m2 - M);
    m = M;
  }
  if (lane == 0) lse[row] = m + logf(s);
}

__global__ __launch_bounds__(256) void sub_kernel(float* __restrict__ logits,
                                                  const float* __restrict__ lse){
  size_t row = blockIdx.x;
  float l = lse[row];
  float4* p4 = (float4*)(logits + row * (size_t)V_DIM);
  for (int i = threadIdx.x; i < V_DIM/4; i += 256){
    float4 v = p4[i];
    v.x -= l; v.y -= l; v.z -= l; v.w -= l;
    p4[i] = v;
  }
}

// ---------------- launch ----------------
extern "C" void kernel_launch(void* const* d_in, const int* in_sizes, int n_in,
                              void* d_out, int out_size, void* d_ws, size_t ws_size,
                              hipStream_t stream)
{
  const float* input  = (const float*)d_in[0];
  const float* hidden = (const float*)d_in[1];
  const float* w_ic   = (const float*)d_in[2];
  const float* w_ix   = (const float*)d_in[3];
  const float* w_fc   = (const float*)d_in[4];
  const float* w_fx   = (const float*)d_in[5];
  const float* b_i    = (const float*)d_in[6];
  const float* b_f    = (const float*)d_in[7];
  const float* W_out  = (const float*)d_in[8];
  const float* b_out  = (const float*)d_in[9];
  float* out = (float*)d_out;

  char* ws = (char*)d_ws;
  ushort* wout_bf = (ushort*)(ws + 0);          // 65,536,000
  ushort* in_hi   = (ushort*)(ws + 65536000);   // 8,388,608 (dead after split-gemm)
  ushort* in_lo   = (ushort*)(ws + 73924608);   // 8,388,608 (dead after split-gemm)
  ushort* wx_hi   = (ushort*)(ws + 82313216);   // 4,194,304 (dead after split-gemm)
  ushort* wx_lo   = (ushort*)(ws + 86507520);
  ushort* wc_hi   = (ushort*)(ws + 90701824);
  ushort* wc_lo   = (ushort*)(ws + 94896128);
  ushort* out_bf  = (ushort*)(ws + 99090432);   // bf16(c_t) hi, all T
  unsigned* bar   = (unsigned*)(ws + 107479040);
  ushort* ch_init = (ushort*)(ws + 107479296);
  ushort* cl_init = (ushort*)(ws + 107544832);  // end: 107,610,368
  // overlays:
  ushort* cl_all  = in_hi;                       // [T][32][1024] lo residuals (during ran_all)
  float*  pmax    = (float*)in_lo;               // [4096][250] (after ran_all)
  float*  psum    = (float*)(ws + 78020608);
  float*  lse     = (float*)wx_hi;               // [4096]
  float*  ixfx    = out;                         // [4096][2048] scratch in logits region

  cast_bf16_kernel <<<2048,256,0,stream>>>(W_out, wout_bf, V_DIM*H_DIM/4);
  cast_split_kernel<<<1024,256,0,stream>>>(input, in_hi, in_lo, MROWS*H_DIM/4);
  cast_split_kernel<<<256,256,0,stream>>>(w_ix, wx_hi,             wx_lo,             H_DIM*H_DIM/4);
  cast_split_kernel<<<256,256,0,stream>>>(w_fx, wx_hi+H_DIM*H_DIM, wx_lo+H_DIM*H_DIM, H_DIM*H_DIM/4);
  cast_split_kernel<<<256,256,0,stream>>>(w_ic, wc_hi,             wc_lo,             H_DIM*H_DIM/4);
  cast_split_kernel<<<256,256,0,stream>>>(w_fc, wc_hi+H_DIM*H_DIM, wc_lo+H_DIM*H_DIM, H_DIM*H_DIM/4);

  // ixfx = input @ [w_ix; w_fx]^T (split-bf16, fused)
  gemm_bt_split<<<32*16,256,0,stream>>>(in_hi, in_lo, wx_hi, wx_lo, ixfx, 2048, H_DIM, 16);

  init_c_kernel<<<128,256,0,stream>>>(hidden, ch_init, cl_init, bar);

  ran_all<<<NBLK,512,0,stream>>>(ch_init, cl_init, cl_all, hidden, wc_hi, wc_lo, b_i, b_f,
                                 ixfx, input, out_bf, out + (size_t)MROWS*V_DIM, bar);

  // logits + fused LSE partials
  gemm_bt<<<32*250,256,0,stream>>>(out_bf, wout_bf, out, b_out, V_DIM, H_DIM, 250, 1, pmax, psum);
  lse_reduce<<<MROWS,64,0,stream>>>(pmax, psum, lse, 250);
  sub_kernel<<<MROWS,256,0,stream>>>(out, lse);
}